// Round 1
// baseline (489.432 us; speedup 1.0000x reference)
//
#include <hip/hip_runtime.h>
#include <stdint.h>

// Problem constants (match reference)
#define S_TOK 16384
#define MDIM  1024
#define NEXP  64
#define CAP   256   // ceil(S/E * 1.0), >= MIN_CAPACITY

static constexpr size_t SEC    = (size_t)S_TOK * NEXP * CAP;  // 268435456
static constexpr size_t CW_OFF = 1;                            // combine_weights
static constexpr size_t DM_OFF = 1 + SEC;                      // dispatch_mask
static constexpr size_t EC_OFF = 1 + 2 * SEC;                  // exp_counts (as float)
static constexpr size_t AL_OFF = EC_OFF + NEXP;                // alpha

// ---------------- Threefry-2x32-20 == jax.random.uniform(key(42), (S,E)) ----------------
__device__ __forceinline__ uint32_t rotl32(uint32_t x, int n) {
  return (x << n) | (x >> (32 - n));
}

// u at flat index i = s*NEXP + e of jax.random.uniform(jax.random.key(42), (S_TOK, NEXP))
__device__ float jax_u01(uint32_t i) {
  const uint32_t half = (uint32_t)(S_TOK * NEXP / 2);  // 524288 (size is even)
  uint32_t x0, x1;
  const bool hi = (i >= half);
  if (hi) { x0 = i - half; x1 = i; } else { x0 = i; x1 = i + half; }
  const uint32_t ks0 = 0u;                       // key(42) -> [0, 42]
  const uint32_t ks1 = 42u;
  const uint32_t ks2 = 0x1BD11BDAu ^ ks0 ^ ks1;
  x0 += ks0; x1 += ks1;
#define TF_R(r) { x0 += x1; x1 = rotl32(x1, (r)); x1 ^= x0; }
  TF_R(13) TF_R(15) TF_R(26) TF_R(6)
  x0 += ks1; x1 += ks2 + 1u;
  TF_R(17) TF_R(29) TF_R(16) TF_R(24)
  x0 += ks2; x1 += ks0 + 2u;
  TF_R(13) TF_R(15) TF_R(26) TF_R(6)
  x0 += ks0; x1 += ks1 + 3u;
  TF_R(17) TF_R(29) TF_R(16) TF_R(24)
  x0 += ks1; x1 += ks2 + 4u;
  TF_R(13) TF_R(15) TF_R(26) TF_R(6)
  x0 += ks2; x1 += ks0 + 5u;
#undef TF_R
  const uint32_t bits = hi ? x1 : x0;
  return __uint_as_float((bits >> 9) | 0x3F800000u) - 1.0f;  // [0,1)
}

// ---------------- K1: logits GEMM (fp32) + softmax + argmax/alpha/u/colsum/counts ----------------
// 256 blocks x 256 threads. Block b owns tokens [b*64, b*64+64).
// LDS tiles: xs[token][k] (natural), wsh[expert][k] with XOR-swizzled float4 slots
// so the compute-phase b-reads (stride-68 rows across 16 lanes) are bank-conflict-free.
__global__ __launch_bounds__(256) void k_gate(
    const float* __restrict__ x, const float* __restrict__ wg,
    float* __restrict__ out,
    int* __restrict__ expert_ws, float* __restrict__ uval_ws,
    float* __restrict__ alpha_ws, float* __restrict__ colsum_ws,
    int* __restrict__ counts_ws)
{
  __shared__ float xs[64][68];   // 68-float rows keep float4 slots 16B-aligned
  __shared__ float wsh[64][68];

  const int tid  = threadIdx.x;
  const int tok0 = blockIdx.x * 64;
  const int tr   = tid >> 4;   // token group 0..15 (4 tokens each)
  const int tc   = tid & 15;   // expert group 0..15 (4 experts each)

  float acc[4][4] = {};

  for (int kc = 0; kc < MDIM; kc += 64) {
    __syncthreads();
    // Stage 64x64 x-tile and full-w k-slice, coalesced float4 loads.
#pragma unroll
    for (int i = 0; i < 4; ++i) {
      const int r = (tid >> 4) + 16 * i;   // row 0..63 (token or expert)
      const int f = tid & 15;              // float4 column 0..15
      const float4 xv = *(const float4*)(x  + (size_t)(tok0 + r) * MDIM + kc + f * 4);
      *(float4*)(&xs[r][f * 4]) = xv;
      const float4 wv = *(const float4*)(wg + (size_t)r * MDIM + kc + f * 4);
      const int fs = f ^ ((r >> 2) & 7);   // XOR swizzle (bank-conflict-free reads)
      *(float4*)(&wsh[r][fs * 4]) = wv;
    }
    __syncthreads();
#pragma unroll
    for (int k4 = 0; k4 < 16; ++k4) {
      float4 a[4], b[4];
#pragma unroll
      for (int i = 0; i < 4; ++i)
        a[i] = *(const float4*)(&xs[tr * 4 + i][k4 * 4]);
#pragma unroll
      for (int j = 0; j < 4; ++j) {
        const int e  = tc * 4 + j;
        const int fs = k4 ^ ((e >> 2) & 7);
        b[j] = *(const float4*)(&wsh[e][fs * 4]);
      }
#pragma unroll
      for (int i = 0; i < 4; ++i)
#pragma unroll
        for (int j = 0; j < 4; ++j)
          acc[i][j] += a[i].x * b[j].x + a[i].y * b[j].y +
                       a[i].z * b[j].z + a[i].w * b[j].w;
    }
  }

  // Dump logits tile to LDS (reuse xs)
  __syncthreads();
#pragma unroll
  for (int i = 0; i < 4; ++i)
#pragma unroll
    for (int j = 0; j < 4; ++j)
      xs[tr * 4 + i][tc * 4 + j] = acc[i][j];
  __syncthreads();

  // Per-token softmax / argmax / alpha / RNG (threads 0..63, one token each)
  if (tid < 64) {
    const int t = tid;
    float mx = -3.0e38f; int am = 0;
    for (int e = 0; e < NEXP; ++e) {
      const float v = xs[t][e];
      if (v > mx) { mx = v; am = e; }   // strict '>' == jnp.argmax first-max
    }
    float sum = 0.f;
    for (int e = 0; e < NEXP; ++e) {
      const float g = expf(xs[t][e] - mx);
      xs[t][e] = g;
      sum += g;
    }
    const float inv = 1.0f / sum;        // == gate at argmax == alpha
    for (int e = 0; e < NEXP; ++e) xs[t][e] *= inv;

    const int s = tok0 + t;
    expert_ws[s] = am;
    alpha_ws[s]  = inv;
    out[AL_OFF + s] = inv;
    uval_ws[s] = jax_u01((uint32_t)s * (uint32_t)NEXP + (uint32_t)am);
    atomicAdd(&counts_ws[am], 1);
  }
  __syncthreads();

  // Column sums of gates (for me / l_aux), one expert per thread 0..63
  if (tid < 64) {
    float s = 0.f;
    for (int t = 0; t < 64; ++t) s += xs[t][tid];
    colsum_ws[(size_t)blockIdx.x * 64 + tid] = s;
  }
}

// ---------------- K2: per-expert capacity selection + sparse scatter ----------------
// 64 blocks (one per expert) x 256 threads. Reproduces lax.top_k tie semantics:
// keep tokens with rank < CAP under (u desc, token idx asc); slot = rank among kept
// by ascending token idx (== cumsum semantics).
__global__ __launch_bounds__(256) void k_select(
    const int* __restrict__ expert_ws, const float* __restrict__ uval_ws,
    const float* __restrict__ alpha_ws, float* __restrict__ out)
{
  __shared__ float su[1024];
  __shared__ int   sidx[1024];
  __shared__ int   skept[1024];
  __shared__ int   scnt;

  const int e   = blockIdx.x;
  const int tid = threadIdx.x;
  if (tid == 0) scnt = 0;
  __syncthreads();

  for (int s = tid; s < S_TOK; s += 256) {
    if (expert_ws[s] == e) {
      const int p = atomicAdd(&scnt, 1);
      if (p < 1024) { su[p] = uval_ws[s]; sidx[p] = s; }  // n ~ 256±16; 1024 is >40σ headroom
    }
  }
  __syncthreads();
  const int n = min(scnt, 1024);

  for (int t = tid; t < n; t += 256) {
    int keep = 1;
    if (n > CAP) {
      const float ut = su[t];
      const int   it = sidx[t];
      int r = 0;
      for (int j = 0; j < n; ++j) {
        const float uj = su[j];
        r += (uj > ut) || (uj == ut && sidx[j] < it);
      }
      keep = (r < CAP);
    }
    skept[t] = keep;
  }
  __syncthreads();

  for (int t = tid; t < n; t += 256) {
    if (!skept[t]) continue;
    const int it = sidx[t];
    int slot = 0;
    for (int j = 0; j < n; ++j) slot += (skept[j] && (sidx[j] < it));
    const size_t base = CW_OFF + ((size_t)it * NEXP + e) * CAP + (size_t)slot;
    out[base]       = alpha_ws[it];  // combine_weights
    out[base + SEC] = 1.0f;          // dispatch_mask (bool as 1.0f)
  }
}

// ---------------- K3: l_aux + exp_counts ----------------
__global__ __launch_bounds__(64) void k_final(
    const float* __restrict__ colsum_ws, const int* __restrict__ counts_ws,
    float* __restrict__ out)
{
  const int e = threadIdx.x;  // 0..63
  float s = 0.f;
  for (int b = 0; b < 256; ++b) s += colsum_ws[(size_t)b * 64 + e];  // fixed order: deterministic
  const float me = s / (float)S_TOK;
  const int   cnt = counts_ws[e];
  const float ce = (float)cnt / (float)S_TOK;
  out[EC_OFF + e] = (float)cnt;
  float v = me * ce;
#pragma unroll
  for (int off = 32; off > 0; off >>= 1) v += __shfl_down(v, off, 64);
  if (e == 0) out[0] = v * (float)NEXP;
}

// ---------------- launch ----------------
extern "C" void kernel_launch(void* const* d_in, const int* in_sizes, int n_in,
                              void* d_out, int out_size, void* d_ws, size_t ws_size,
                              hipStream_t stream)
{
  const float* x  = (const float*)d_in[0];
  const float* wg = (const float*)d_in[1];
  float* out = (float*)d_out;

  // workspace layout (262,400 bytes total)
  char* ws = (char*)d_ws;
  int*   expert_ws = (int*)  (ws + 0);        // S ints
  float* uval_ws   = (float*)(ws + 65536);    // S floats
  float* alpha_ws  = (float*)(ws + 131072);   // S floats
  float* colsum_ws = (float*)(ws + 196608);   // 256*64 floats
  int*   counts_ws = (int*)  (ws + 262144);   // 64 ints

  // Clear entire output (poisoned 0xAA before timing); sparse nonzeros written after.
  hipMemsetAsync(d_out, 0, (size_t)out_size * sizeof(float), stream);
  hipMemsetAsync(counts_ws, 0, NEXP * sizeof(int), stream);

  k_gate  <<<S_TOK / 64, 256, 0, stream>>>(x, wg, out, expert_ws, uval_ws,
                                           alpha_ws, colsum_ws, counts_ws);
  k_select<<<NEXP,       256, 0, stream>>>(expert_ws, uval_ws, alpha_ws, out);
  k_final <<<1,           64, 0, stream>>>(colsum_ws, counts_ws, out);
}